// Round 7
// baseline (75.923 us; speedup 1.0000x reference)
//
#include <hip/hip_runtime.h>
#include <hip/hip_bf16.h>
#include <hip/hip_fp16.h>
#include <math.h>

// ---- types ----
using f32x4  = __attribute__((ext_vector_type(4))) float;
using half8  = __attribute__((ext_vector_type(8))) _Float16;
using uint4v = __attribute__((ext_vector_type(4))) unsigned int;

#define WAITV(N) asm volatile("s_waitcnt vmcnt(" #N ")" ::: "memory")
#define LGKM0    asm volatile("s_waitcnt lgkmcnt(0)" ::: "memory")

__device__ __forceinline__ unsigned short f32_to_f16u(float f) {
  return __half_as_ushort(__float2half(f));
}
__device__ __forceinline__ float f16u_to_f32(unsigned short h) {
  return __half2float(__ushort_as_half(h));
}
__device__ __forceinline__ unsigned int pk2(float a, float b) {
  return (unsigned int)f32_to_f16u(a) | ((unsigned int)f32_to_f16u(b) << 16);
}
__device__ __forceinline__ f32x4 mfma16(half8 a, half8 b, f32x4 c) {
  return __builtin_amdgcn_mfma_f32_16x16x32_f16(a, b, c, 0, 0, 0);
}
__device__ __forceinline__ void gload_lds16(void* lds, const void* g) {
  __builtin_amdgcn_global_load_lds(
      (const __attribute__((address_space(1))) unsigned int*)g,
      (__attribute__((address_space(3))) unsigned int*)lds, 16, 0, 0);
}
__device__ __forceinline__ float gelu_exact(float x) {
  return 0.5f * x * (1.0f + erff(x * 0.70710678118654752440f));
}

// ---- problem constants ----
// B=32768, D=768, H1=256, E=128, N=500(pad 512), K_imp=902(pad 960)

// ---------------------------------------------------------------------------
// prep: W1T via coalesced LDS-tile transpose (blocks 0..47); rest idx-based.
// ---------------------------------------------------------------------------
__global__ __launch_bounds__(256) void k_prep(
    const float* __restrict__ enc_w1, const float* __restrict__ enc_w2,
    const float* __restrict__ imp_w1, const float* __restrict__ cent,
    const float* __restrict__ reward, const float* __restrict__ tsp,
    const float* __restrict__ emo,
    unsigned short* __restrict__ W1T, unsigned short* __restrict__ W2T,
    unsigned short* __restrict__ impW1T, unsigned short* __restrict__ centC,
    float* __restrict__ c_n, unsigned short* __restrict__ tail) {
  __shared__ float ld[64][65];
  const int bx = blockIdx.x, t = threadIdx.x;
  if (bx < 48) {                       // W1T [256][768] tile-transpose 64x64
    int tk = bx % 12, tn = bx / 12;
    int k0 = tk * 64, n0 = tn * 64;
    int cn = t & 63, r4 = t >> 6;
#pragma unroll
    for (int pass = 0; pass < 16; ++pass) {
      int kk = pass * 4 + r4;
      ld[kk][cn] = enc_w1[(size_t)(k0 + kk) * 256 + n0 + cn];
    }
    __syncthreads();
    int ck = t & 63, rn4 = t >> 6;
#pragma unroll
    for (int pass = 0; pass < 16; ++pass) {
      int nn = pass * 4 + rn4;
      W1T[(size_t)(n0 + nn) * 768 + k0 + ck] = f32_to_f16u(ld[ck][nn]);
    }
    return;
  }
  int idx = (bx - 48) * 256 + t;
  if (idx < 128 * 256) {               // W2T [128][256]
    int n = idx >> 8, k = idx & 255;
    W2T[idx] = f32_to_f16u(enc_w2[k * 128 + n]);
  }
  if (idx < 64 * 960) {                // impW1T [64][960], k>=902 zero
    int n = idx / 960, k = idx - n * 960;
    impW1T[idx] = (k < 902) ? f32_to_f16u(imp_w1[k * 64 + n]) : (unsigned short)0;
  }
  if (idx < 512 * 128) {               // centC [512][128], rows>=500 zero
    int n = idx >> 7, k = idx & 127;
    centC[idx] = (n < 500) ? f32_to_f16u(cent[n * 128 + k]) : (unsigned short)0;
  }
  if (idx < 512) {                     // centroid norms (of f16-rounded values)
    float s = 0.f;
    if (idx < 500) {
      const f32x4* p = (const f32x4*)(cent + idx * 128);
#pragma unroll 8
      for (int j = 0; j < 32; ++j) {
        f32x4 v = p[j];
#pragma unroll
        for (int e = 0; e < 4; ++e) {
          float q = (float)(_Float16)v[e];
          s += q * q;
        }
      }
    }
    c_n[idx] = sqrtf(s);
  }
  if (idx < 32768) {                   // tail pack
    f32x4 e4 = *(const f32x4*)(emo + (size_t)idx * 4);
    unsigned short* tp = tail + (size_t)idx * 8;
    tp[0] = f32_to_f16u(reward[idx]);
    tp[1] = f32_to_f16u(tsp[idx]);
    tp[2] = f32_to_f16u(e4[0]); tp[3] = f32_to_f16u(e4[1]);
    tp[4] = f32_to_f16u(e4[2]); tp[5] = f32_to_f16u(e4[3]);
    tp[6] = 0; tp[7] = 0;
  }
}

// ---------------------------------------------------------------------------
// fused enc1+imp, 64 rows/block, 512 blocks (2 blocks/CU), 512 thr (8 waves).
// Wave w (wr=w>>2, wc=w&3): enc 32x64 (acc1 2x4), imp 32x16 (acc2 2).
// LDS 72KB: A dbuf 2x8K | tail slot 8K | B1 single 32K | B2 dbuf 2x8K.
// Per step: front-read B1/B2 frags -> regs; bar; issue B1(it+1) (flight
// covered by MFMA phase); convW; issue A/B2(it+2); setprio'd MFMA (A inline);
// WAITV(3) (counted, never 0); bar.
// ---------------------------------------------------------------------------
__global__ __launch_bounds__(512, 4) void k_encimp(
    const float* __restrict__ cue, const float* __restrict__ internal,
    const float* __restrict__ emo,
    const unsigned short* __restrict__ W1T, const unsigned short* __restrict__ impW1T,
    const unsigned short* __restrict__ tail,
    const float* __restrict__ b1, const float* __restrict__ ib1,
    const float* __restrict__ iw2, const float* __restrict__ ib2,
    unsigned short* __restrict__ h1, float* __restrict__ out) {
  __shared__ unsigned char sm[73728];
  const int t = threadIdx.x;
  const int lane = t & 63, w = t >> 6;
  const int wr = w >> 2, wc = w & 3;
  const int g = lane >> 4, c = lane & 15;
  const int row0 = blockIdx.x * 64;

  const int srow = t >> 3, q8 = t & 7;
  const int abyte = srow * 128 + q8 * 16;
  const int aswz = (srow & 7) << 4;
  const int myrow = row0 + srow;

  f32x4 aLo, aHi;
  auto issueA = [&](int j) {
    const float* s = (j < 12)
        ? (cue + (size_t)myrow * 768 + j * 64 + q8 * 8)
        : (internal + (size_t)myrow * 128 + (j - 12) * 64 + q8 * 8);
    aLo = *(const f32x4*)s;
    aHi = *(const f32x4*)(s + 4);
  };
  auto convWrite = [&](int buf) {
    uint4v u = {pk2(aLo[0], aLo[1]), pk2(aLo[2], aLo[3]),
                pk2(aHi[0], aHi[1]), pk2(aHi[2], aHi[3])};
    *(uint4v*)(sm + buf * 8192 + (abyte ^ aswz)) = u;
  };
  auto issueB1 = [&](int j) {
#pragma unroll
    for (int i = 0; i < 4; ++i) {
      int L = i * 8192 + t * 16;
      int nl = L >> 7, x = L & 127;
      gload_lds16(sm + 24576 + i * 8192 + w * 1024,
                  (const unsigned char*)W1T + ((size_t)nl * 768 + j * 64) * 2 +
                      (x ^ ((nl & 7) << 4)));
    }
  };
  auto issueB2 = [&](int j, int buf) {
    int L = t * 16, nl = L >> 7, x = L & 127;
    gload_lds16(sm + 57344 + buf * 8192 + w * 1024,
                (const unsigned char*)impW1T + (size_t)nl * 1920 + j * 128 +
                    (x ^ ((nl & 7) << 4)));
  };

  f32x4 acc1[2][4];
  f32x4 acc2[2];
#pragma unroll
  for (int i = 0; i < 2; ++i) {
    acc2[i] = f32x4{0.f, 0.f, 0.f, 0.f};
#pragma unroll
    for (int j = 0; j < 4; ++j) acc1[i][j] = f32x4{0.f, 0.f, 0.f, 0.f};
  }

  // ds-read version used only in the (imp-only) tail steps
  auto mfma_step = [&](int abuf, int b2buf, bool enc) {
    const unsigned char* Ab  = sm + abuf * 8192;
    const unsigned char* Bb2 = sm + 57344 + b2buf * 8192;
#pragma unroll
    for (int ks = 0; ks < 2; ++ks) {
      half8 af[2];
#pragma unroll
      for (int mf = 0; mf < 2; ++mf) {
        int m = wr * 32 + mf * 16 + c;
        af[mf] = *(const half8*)(Ab + m * 128 + ((ks * 64 + g * 16) ^ ((m & 7) << 4)));
      }
      {
        int n2 = wc * 16 + c;
        half8 b2f = *(const half8*)(Bb2 + n2 * 128 + ((ks * 64 + g * 16) ^ ((n2 & 7) << 4)));
        acc2[0] = mfma16(af[0], b2f, acc2[0]);
        acc2[1] = mfma16(af[1], b2f, acc2[1]);
      }
      if (enc) {
#pragma unroll
        for (int nf = 0; nf < 4; ++nf) {
          int n = wc * 64 + nf * 16 + c;
          half8 bf = *(const half8*)(sm + 24576 + n * 128 +
                                     ((ks * 64 + g * 16) ^ ((n & 7) << 4)));
          acc1[0][nf] = mfma16(af[0], bf, acc1[0][nf]);
          acc1[1][nf] = mfma16(af[1], bf, acc1[1][nf]);
        }
      }
    }
  };

  // ---- prologue: tail slot + tile0 staged; tile1 A/B2 in flight ----
  {
    uint4v tl = {0u, 0u, 0u, 0u};
    if (q8 == 0) tl = *(const uint4v*)(tail + (size_t)myrow * 8);
    issueA(0); issueB1(0); issueB2(0, 0);
    *(uint4v*)(sm + 16384 + (abyte ^ aswz)) = tl;   // tail tile (abuf index 2)
    convWrite(0);                                    // A(0) -> abuf0
    issueA(1); issueB2(1, 1);
    WAITV(3);                                        // B1(0),B2(0) landed
    LGKM0;
    __builtin_amdgcn_s_barrier();
  }

  int p = 0;
  for (int it = 0; it < 12; ++it) {
    // ---- front-read this step's B1/B2 fragments into registers ----
    half8 bf[2][4], b2f[2];
#pragma unroll
    for (int ks = 0; ks < 2; ++ks) {
#pragma unroll
      for (int nf = 0; nf < 4; ++nf) {
        int n = wc * 64 + nf * 16 + c;
        bf[ks][nf] = *(const half8*)(sm + 24576 + n * 128 +
                                     ((ks * 64 + g * 16) ^ ((n & 7) << 4)));
      }
      int n2 = wc * 16 + c;
      b2f[ks] = *(const half8*)(sm + 57344 + p * 8192 + n2 * 128 +
                                ((ks * 64 + g * 16) ^ ((n2 & 7) << 4)));
    }
    LGKM0;
    __builtin_amdgcn_s_barrier();      // bar1: all front-reads done
    // ---- issue next B1 ASAP (flight covered by MFMA phase below) ----
    if (it < 11) issueB1(it + 1);
    convWrite(p ^ 1);                  // A(it+1) regs -> abuf p^1
    issueA(it + 2);                    // cue (<=11) or internal (12,13)
    issueB2(it + 2, p);                // overwrite b2buf p
    // ---- MFMA phase (B from regs, A inline from stable buf p) ----
    __builtin_amdgcn_s_setprio(1);
#pragma unroll
    for (int ks = 0; ks < 2; ++ks) {
      half8 af[2];
#pragma unroll
      for (int mf = 0; mf < 2; ++mf) {
        int m = wr * 32 + mf * 16 + c;
        af[mf] = *(const half8*)(sm + p * 8192 + m * 128 +
                                 ((ks * 64 + g * 16) ^ ((m & 7) << 4)));
      }
      acc2[0] = mfma16(af[0], b2f[ks], acc2[0]);
      acc2[1] = mfma16(af[1], b2f[ks], acc2[1]);
#pragma unroll
      for (int nf = 0; nf < 4; ++nf) {
        acc1[0][nf] = mfma16(af[0], bf[ks][nf], acc1[0][nf]);
        acc1[1][nf] = mfma16(af[1], bf[ks][nf], acc1[1][nf]);
      }
    }
    __builtin_amdgcn_s_setprio(0);
    WAITV(3);                          // B1(it+1)+B2(it+1) landed; 3 in flight
    LGKM0;
    __builtin_amdgcn_s_barrier();      // bar2
    p ^= 1;
  }
  // p == 0 here. Steps 12,13 (internal), 14 (tail): imp only.
  mfma_step(0, 0, false);              // tile 12
  convWrite(1);                        // A(13)
  LGKM0;
  __builtin_amdgcn_s_barrier();
  issueB2(14, 0);
  WAITV(1);                            // B2(13) landed
  __builtin_amdgcn_s_barrier();
  mfma_step(1, 1, false);              // tile 13
  LGKM0;
  __builtin_amdgcn_s_barrier();
  WAITV(0);                            // B2(14) landed
  __builtin_amdgcn_s_barrier();
  mfma_step(2, 0, false);              // tile 14 (tail slot)

  // ---- enc1 epilogue: bias + exact gelu -> h1 (global, f16) ----
  float bias1[4];
#pragma unroll
  for (int nf = 0; nf < 4; ++nf) bias1[nf] = b1[wc * 64 + nf * 16 + c];
#pragma unroll
  for (int mf = 0; mf < 2; ++mf)
#pragma unroll
    for (int nf = 0; nf < 4; ++nf)
#pragma unroll
      for (int rr = 0; rr < 4; ++rr) {
        float x = acc1[mf][nf][rr] + bias1[nf];
        int m = row0 + wr * 32 + mf * 16 + g * 4 + rr;
        int n = wc * 64 + nf * 16 + c;
        h1[(size_t)m * 256 + n] = f32_to_f16u(gelu_exact(x));
      }

  // ---- imp epilogue: gelu*w2, 16-lane reduce -> LDS partials -> final ----
  {
    float* s_p = (float*)(sm + 24576);  // B1 area, dead now
    float b1v = ib1[wc * 16 + c];
    float w2v = iw2[wc * 16 + c];
#pragma unroll
    for (int mf = 0; mf < 2; ++mf)
#pragma unroll
      for (int rr = 0; rr < 4; ++rr) {
        float v = gelu_exact(acc2[mf][rr] + b1v) * w2v;
        v += __shfl_xor(v, 1);
        v += __shfl_xor(v, 2);
        v += __shfl_xor(v, 4);
        v += __shfl_xor(v, 8);
        if (c == 0) s_p[(wr * 32 + mf * 16 + g * 4 + rr) * 4 + wc] = v;
      }
    __syncthreads();
    if (t < 64) {
      float ssum = s_p[t * 4 + 0] + s_p[t * 4 + 1] + s_p[t * 4 + 2] + s_p[t * 4 + 3];
      int rowA = row0 + t;
      float z = ssum + ib2[0];
      float sig = 1.0f / (1.0f + expf(-z));
      f32x4 e4 = *(const f32x4*)(emo + (size_t)rowA * 4);
      float m4 = 0.25f * (e4[0] + e4[1] + e4[2] + e4[3]);
      out[(size_t)rowA * 6 + 5] = sig * m4;
    }
  }
}

// ---------------------------------------------------------------------------
// enc2: enc = h1 @ W2 + b2   [32768,256]x[256,128] -> f16 [32768][128]
// ---------------------------------------------------------------------------
__global__ __launch_bounds__(256) void k_enc2(
    const unsigned short* __restrict__ h1, const unsigned short* __restrict__ W2T,
    const float* __restrict__ b2, unsigned short* __restrict__ enc) {
  __shared__ unsigned char smA[16384];
  __shared__ unsigned char smB[8192];
  const int t = threadIdx.x;
  const int lane = t & 63, w = t >> 6;
  const int wr = w >> 1, wc = w & 1;
  const int g = lane >> 4, c = lane & 15;
  const int row0 = blockIdx.x * 128;
  const int n0 = blockIdx.y * 64;

  f32x4 acc[4][2];
#pragma unroll
  for (int i = 0; i < 4; ++i)
#pragma unroll
    for (int j = 0; j < 2; ++j) acc[i][j] = f32x4{0.f, 0.f, 0.f, 0.f};

  for (int it = 0; it < 4; ++it) {
    __syncthreads();
#pragma unroll
    for (int i = 0; i < 4; ++i) {
      int L = i * 4096 + t * 16;
      int rl = L >> 7, x = L & 127;
      const unsigned char* gs = (const unsigned char*)h1 +
          (size_t)(row0 + rl) * 512 + it * 128 + (x ^ ((rl & 7) << 4));
      gload_lds16(smA + i * 4096 + w * 1024, gs);
    }
#pragma unroll
    for (int i = 0; i < 2; ++i) {
      int L = i * 4096 + t * 16;
      int nl = L >> 7, x = L & 127;
      const unsigned char* gs = (const unsigned char*)W2T +
          (size_t)(n0 + nl) * 512 + it * 128 + (x ^ ((nl & 7) << 4));
      gload_lds16(smB + i * 4096 + w * 1024, gs);
    }
    __syncthreads();
#pragma unroll
    for (int ks = 0; ks < 2; ++ks) {
      half8 af[4], bf[2];
#pragma unroll
      for (int mf = 0; mf < 4; ++mf) {
        int m = wr * 64 + mf * 16 + c;
        af[mf] = *(const half8*)(smA + m * 128 + (((ks * 64) + g * 16) ^ ((m & 7) << 4)));
      }
#pragma unroll
      for (int nf = 0; nf < 2; ++nf) {
        int n = wc * 32 + nf * 16 + c;
        bf[nf] = *(const half8*)(smB + n * 128 + (((ks * 64) + g * 16) ^ ((n & 7) << 4)));
      }
#pragma unroll
      for (int mf = 0; mf < 4; ++mf)
#pragma unroll
        for (int nf = 0; nf < 2; ++nf)
          acc[mf][nf] = mfma16(af[mf], bf[nf], acc[mf][nf]);
    }
  }
  float bias[2];
#pragma unroll
  for (int nf = 0; nf < 2; ++nf) bias[nf] = b2[n0 + wc * 32 + nf * 16 + c];
#pragma unroll
  for (int mf = 0; mf < 4; ++mf)
#pragma unroll
    for (int nf = 0; nf < 2; ++nf)
#pragma unroll
      for (int r = 0; r < 4; ++r) {
        float x = acc[mf][nf][r] + bias[nf];
        int m = row0 + wr * 64 + mf * 16 + g * 4 + r;
        int n = n0 + wc * 32 + nf * 16 + c;
        enc[(size_t)m * 128 + n] = f32_to_f16u(x);
      }
}

// ---------------------------------------------------------------------------
// sims + top5 (streaming): per block 64 rows; each wave 16 rows x 512 cols.
// ---------------------------------------------------------------------------
__global__ __launch_bounds__(256) void k_sims(
    const unsigned short* __restrict__ enc, const unsigned short* __restrict__ centC,
    const float* __restrict__ c_n, float* __restrict__ out) {
  __shared__ unsigned char smC[32768];
  __shared__ float s_en[64];
  const int t = threadIdx.x, lane = t & 63, w = t >> 6;
  const int g = lane >> 4, c = lane & 15;
  const int row0 = blockIdx.x * 64;

  {
    int r = t >> 2, q = t & 3;
    const unsigned char* base = (const unsigned char*)enc + (size_t)(row0 + r) * 256 + q * 64;
    float s = 0.f;
#pragma unroll
    for (int j = 0; j < 4; ++j) {
      uint4v u = *(const uint4v*)(base + j * 16);
#pragma unroll
      for (int e = 0; e < 4; ++e) {
        float lo = f16u_to_f32((unsigned short)(u[e] & 0xFFFFu));
        float hi = f16u_to_f32((unsigned short)(u[e] >> 16));
        s += lo * lo + hi * hi;
      }
    }
    s += __shfl_xor(s, 1);
    s += __shfl_xor(s, 2);
    if (q == 0) s_en[r] = sqrtf(s);
  }
  __syncthreads();

  float en[4];
#pragma unroll
  for (int r = 0; r < 4; ++r) en[r] = s_en[w * 16 + g * 4 + r];

  half8 af[4];
  {
    const unsigned char* abase =
        (const unsigned char*)enc + (size_t)(row0 + w * 16 + c) * 256 + g * 16;
#pragma unroll
    for (int kk = 0; kk < 4; ++kk) af[kk] = *(const half8*)(abase + kk * 64);
  }

  unsigned int top5[4][5];
#pragma unroll
  for (int r = 0; r < 4; ++r)
#pragma unroll
    for (int s5 = 0; s5 < 5; ++s5) top5[r][s5] = 0u;

#pragma unroll
  for (int ch = 0; ch < 4; ++ch) {
    __syncthreads();
#pragma unroll
    for (int i = 0; i < 8; ++i) {
      int L = i * 4096 + t * 16;
      int nl = L >> 8, x = L & 255;
      const unsigned char* gs = (const unsigned char*)centC +
          (size_t)(ch * 128 + nl) * 256 + (x ^ ((nl & 7) << 4));
      gload_lds16(smC + i * 4096 + w * 1024, gs);
    }
    __syncthreads();

    f32x4 acc[8];
#pragma unroll
    for (int i = 0; i < 8; ++i) acc[i] = f32x4{0.f, 0.f, 0.f, 0.f};
#pragma unroll
    for (int nfc = 0; nfc < 8; ++nfc) {
      int nl = nfc * 16 + c;
      const unsigned char* bbase = smC + nl * 256;
      int swz = (nl & 7) << 4;
#pragma unroll
      for (int kk = 0; kk < 4; ++kk) {
        half8 bf = *(const half8*)(bbase + ((kk * 64 + g * 16) ^ swz));
        acc[nfc] = mfma16(af[kk], bf, acc[nfc]);
      }
    }

#pragma unroll
    for (int nfc = 0; nfc < 8; ++nfc) {
      int col = ch * 128 + nfc * 16 + c;
      float cnv = c_n[col];
#pragma unroll
      for (int r = 0; r < 4; ++r) {
        float denom = fmaxf(en[r] * cnv, 1e-8f);
        float v = acc[nfc][r] * __builtin_amdgcn_rcpf(denom);
        unsigned int u = __float_as_uint(v);
        u = (u & 0x80000000u) ? ~u : (u | 0x80000000u);
        unsigned int k = (col < 500) ? ((u & 0xFFFFFE00u) | (unsigned)col) : 0u;
        unsigned int t0 = top5[r][0], t1 = top5[r][1], t2 = top5[r][2],
                     t3 = top5[r][3], t4 = top5[r][4];
        top5[r][0] = (k > t0) ? k : t0;
        top5[r][1] = (k > t0) ? t0 : ((k > t1) ? k : t1);
        top5[r][2] = (k > t1) ? t1 : ((k > t2) ? k : t2);
        top5[r][3] = (k > t2) ? t2 : ((k > t3) ? k : t3);
        top5[r][4] = (k > t3) ? t3 : ((k > t4) ? k : t4);
      }
    }
  }

#pragma unroll
  for (int r = 0; r < 4; ++r) {
    int rowA = row0 + w * 16 + g * 4 + r;
    unsigned int h0 = top5[r][0], h1 = top5[r][1], h2 = top5[r][2],
                 h3 = top5[r][3], h4 = top5[r][4];
#pragma unroll
    for (int it5 = 0; it5 < 5; ++it5) {
      unsigned int best = h0;
#pragma unroll
      for (int s = 1; s < 16; s <<= 1) {
        unsigned int o = __shfl_xor(best, s);
        best = (o > best) ? o : best;
      }
      if (c == 0) {
        unsigned int m = best & 0xFFFFFE00u;
        unsigned int uu = (m & 0x80000000u) ? (m ^ 0x80000000u) : ~m;
        out[(size_t)rowA * 6 + it5] = __uint_as_float(uu);
      }
      bool pop = (h0 == best);
      h0 = pop ? h1 : h0;
      h1 = pop ? h2 : h1;
      h2 = pop ? h3 : h2;
      h3 = pop ? h4 : h3;
      h4 = pop ? 0u : h4;
    }
  }
}

// ---------------------------------------------------------------------------
extern "C" void kernel_launch(void* const* d_in, const int* in_sizes, int n_in,
                              void* d_out, int out_size, void* d_ws, size_t ws_size,
                              hipStream_t stream) {
  (void)in_sizes; (void)n_in; (void)out_size; (void)ws_size;
  const float* cue      = (const float*)d_in[0];
  const float* internal = (const float*)d_in[1];
  const float* reward   = (const float*)d_in[2];
  const float* tsp      = (const float*)d_in[3];
  const float* emo      = (const float*)d_in[4];
  const float* cent     = (const float*)d_in[5];
  const float* enc_w1   = (const float*)d_in[6];
  const float* enc_b1   = (const float*)d_in[7];
  const float* enc_w2   = (const float*)d_in[8];
  const float* enc_b2   = (const float*)d_in[9];
  const float* imp_w1   = (const float*)d_in[10];
  const float* imp_b1   = (const float*)d_in[11];
  const float* imp_w2   = (const float*)d_in[12];
  const float* imp_b2   = (const float*)d_in[13];
  float* out = (float*)d_out;

  unsigned char* ws = (unsigned char*)d_ws;
  unsigned short* h1     = (unsigned short*)(ws + 0);         // 16777216
  unsigned short* enc    = (unsigned short*)(ws + 16777216);  //  8388608
  unsigned short* W1T    = (unsigned short*)(ws + 25165824);  //   393216
  unsigned short* W2T    = (unsigned short*)(ws + 25559040);  //    65536
  unsigned short* impW1T = (unsigned short*)(ws + 25624576);  //   122880
  unsigned short* centC  = (unsigned short*)(ws + 25747456);  //   131072
  float*          c_n    = (float*)(ws + 25878528);           //     2048
  unsigned short* tail   = (unsigned short*)(ws + 25880576);  //   524288

  k_prep<<<768, 256, 0, stream>>>(enc_w1, enc_w2, imp_w1, cent, reward, tsp, emo,
                                  W1T, W2T, impW1T, centC, c_n, tail);
  k_encimp<<<512, 512, 0, stream>>>(cue, internal, emo, W1T, impW1T, tail,
                                    enc_b1, imp_b1, imp_w2, imp_b2, h1, out);
  k_enc2<<<dim3(256, 2), 256, 0, stream>>>(h1, W2T, enc_b2, enc);
  k_sims<<<512, 256, 0, stream>>>(enc, centC, c_n, out);
}